// Round 2
// baseline (2266.420 us; speedup 1.0000x reference)
//
#include <hip/hip_runtime.h>

#define BB   256
#define TT   512
#define FF   8
#define HH   256
#define LL   4
#define OO   8
#define BETA 0.8f
#define THRV 1.0f

// d_out layout (floats): outputs | hidden | prev_obs | readout
#define OFF_OUT  0
#define OFF_HID  (BB*TT*OO)                       // 1048576
#define OFF_PREV (OFF_HID + (size_t)BB*TT*LL*HH)  // 135266304
#define OFF_RO   (OFF_PREV + BB*TT*FF)            // 136314880

typedef float nf4 __attribute__((ext_vector_type(4)));

__launch_bounds__(512, 1)
__global__ void snn_kernel(const float* __restrict__ x,
                           const float* __restrict__ hidden_in,
                           const float* __restrict__ readout_in,
                           const float* __restrict__ W1,
                           const float* __restrict__ b1,
                           const float* __restrict__ Wh,
                           const float* __restrict__ bh,
                           const float* __restrict__ Wout,
                           const float* __restrict__ bout,
                           float* __restrict__ out)
{
    __shared__ int   s_list[HH];   // spiking h, pre-multiplied by HH (row offset)
    __shared__ int   s_wcnt[4];
    __shared__ float s_part[HH];
    __shared__ float s_rop[4 * OO];

    const int tid  = threadIdx.x;
    const int b    = blockIdx.x;
    const int h    = tid & (HH - 1);
    const int half = tid >> 8;         // 0: owns state, 1: helper for row-sum
    const int lane = tid & 63;
    const int wave = tid >> 6;

    // prev_obs = x (pure copy), nontemporal
    {
        const nf4* xs = (const nf4*)(x + (size_t)b * TT * FF);
        nf4*       po = (nf4*)(out + OFF_PREV + (size_t)b * TT * FF);
        #pragma unroll
        for (int i = 0; i < (TT * FF / 4) / 512; ++i)
            __builtin_nontemporal_store(xs[tid + i * 512], po + tid + i * 512);
    }

    float m[LL] = {0, 0, 0, 0};
    float w1c[FF];
    float b1c = 0, bhc0 = 0, bhc1 = 0, bhc2 = 0;
    float wo[OO];
    #pragma unroll
    for (int o = 0; o < OO; ++o) wo[o] = 0.0f;
    if (half == 0) {
        const size_t hb = (size_t)b * TT * LL * HH;
        #pragma unroll
        for (int i = 0; i < LL; ++i) m[i] = hidden_in[hb + i * HH + h];
        #pragma unroll
        for (int f = 0; f < FF; ++f) w1c[f] = W1[f * HH + h];
        b1c  = b1[h];
        bhc0 = bh[0 * HH + h]; bhc1 = bh[1 * HH + h]; bhc2 = bh[2 * HH + h];
        #pragma unroll
        for (int o = 0; o < OO; ++o) wo[o] = Wout[h * OO + o];
    }
    float ro = 0, boutc = 0;
    if (tid < OO) { ro = readout_in[(size_t)b * TT * OO + tid]; boutc = bout[tid]; }

    const float* xb     = x + (size_t)b * TT * FF;
    float* hid_out      = out + OFF_HID + (size_t)b * TT * LL * HH;
    float* out_o        = out + OFF_OUT + (size_t)b * TT * OO;
    float* out_r        = out + OFF_RO  + (size_t)b * TT * OO;

    for (int t = 0; t < TT; ++t) {
        float* hrow = hid_out + (size_t)t * LL * HH;
        float c = 0.0f;
        if (half == 0) {
            c = b1c;
            #pragma unroll
            for (int f = 0; f < FF; ++f) c += xb[t * FF + f] * w1c[f];
        }

        // layers 0..2: update mem, share spikes, sparse row-sum of Wh[i]
        #pragma unroll
        for (int i = 0; i < 3; ++i) {
            int spk = 0;
            unsigned long long bmask = 0ull;
            if (half == 0) {
                float mm = m[i];
                float reset = (mm > THRV) ? THRV : 0.0f;
                mm = BETA * mm + c - reset;
                spk = (mm > THRV) ? 1 : 0;
                m[i] = mm;
                __builtin_nontemporal_store(mm, hrow + i * HH + h);
                bmask = __ballot(spk);
                if (lane == 0) s_wcnt[wave] = __popcll(bmask);
            }
            __syncthreads();
            const int n0 = s_wcnt[0], n1 = s_wcnt[1], n2 = s_wcnt[2], n3 = s_wcnt[3];
            const int n = n0 + n1 + n2 + n3;
            if (half == 0 && spk) {
                int base = (wave > 0 ? n0 : 0) + (wave > 1 ? n1 : 0) + (wave > 2 ? n2 : 0);
                int pos = base + __popcll(bmask & ((1ull << lane) - 1ull));
                s_list[pos] = h << 8;   // pre-scaled row offset (h * HH)
            }
            __syncthreads();

            const float* Wb = Wh + i * (HH * HH) + h;   // column h, row stride HH
            float cc = (half == 0) ? (i == 0 ? bhc0 : (i == 1 ? bhc1 : bhc2)) : 0.0f;
            int j = half;               // lower: even entries, upper: odd entries
            while (j + 14 < n) {
                int a0 = s_list[j],      a1 = s_list[j + 2];
                int a2 = s_list[j + 4],  a3 = s_list[j + 6];
                int a4 = s_list[j + 8],  a5 = s_list[j + 10];
                int a6 = s_list[j + 12], a7 = s_list[j + 14];
                float w0 = Wb[a0], w1 = Wb[a1], w2 = Wb[a2], w3 = Wb[a3];
                float w4 = Wb[a4], w5 = Wb[a5], w6 = Wb[a6], w7 = Wb[a7];
                cc += ((w0 + w1) + (w2 + w3)) + ((w4 + w5) + (w6 + w7));
                j += 16;
            }
            while (j < n) { cc += Wb[s_list[j]]; j += 2; }

            if (half == 1) s_part[h] = cc;
            __syncthreads();
            if (half == 0) c = cc + s_part[h];
        }

        // layer 3: mem update + readout (O=8) via per-wave butterfly reduce
        if (half == 0) {
            float mm = m[3];
            float reset = (mm > THRV) ? THRV : 0.0f;
            mm = BETA * mm + c - reset;
            int spk3 = (mm > THRV) ? 1 : 0;
            m[3] = mm;
            __builtin_nontemporal_store(mm, hrow + 3 * HH + h);

            float s = spk3 ? 1.0f : 0.0f;
            float c8[OO];
            #pragma unroll
            for (int o = 0; o < OO; ++o) c8[o] = s * wo[o];
            #pragma unroll
            for (int d = 1; d < 64; d <<= 1) {
                #pragma unroll
                for (int o = 0; o < OO; ++o) c8[o] += __shfl_xor(c8[o], d);
            }
            if (lane == 0) {
                #pragma unroll
                for (int o = 0; o < OO; ++o) s_rop[wave * OO + o] = c8[o];
            }
        }
        __syncthreads();
        if (tid < OO) {
            float s = boutc + s_rop[tid] + s_rop[OO + tid] + s_rop[2 * OO + tid] + s_rop[3 * OO + tid];
            ro = BETA * ro + s;
            __builtin_nontemporal_store(ro, out_o + t * OO + tid);
            __builtin_nontemporal_store(ro, out_r + t * OO + tid);
        }
    }
}

extern "C" void kernel_launch(void* const* d_in, const int* in_sizes, int n_in,
                              void* d_out, int out_size, void* d_ws, size_t ws_size,
                              hipStream_t stream) {
    const float* x       = (const float*)d_in[0];
    const float* hidden  = (const float*)d_in[1];
    // d_in[2] = prev_obs (unused by the recurrence)
    const float* readout = (const float*)d_in[3];
    const float* W1      = (const float*)d_in[4];
    const float* b1      = (const float*)d_in[5];
    const float* Wh      = (const float*)d_in[6];
    const float* bh      = (const float*)d_in[7];
    const float* Wout    = (const float*)d_in[8];
    const float* bout    = (const float*)d_in[9];
    float* out = (float*)d_out;

    snn_kernel<<<dim3(BB), dim3(512), 0, stream>>>(
        x, hidden, readout, W1, b1, Wh, bh, Wout, bout, out);
}